// Round 1
// baseline (159.907 us; speedup 1.0000x reference)
//
#include <hip/hip_runtime.h>
#include <math.h>

#define NL 12
#define NB 2
#define NT 2048
#define ND 2048
#define NC 4
#define NH 48
#define NBT (NB*NT)                 // 4096 tokens
#define BTD ((long)NBT*(long)ND)    // 8388608
#define TOK 8                       // tokens per block in dw_kernel

__device__ __forceinline__ float gelu_exact(float x) {
    return 0.5f * x * (1.0f + erff(x * 0.70710678118654752f));
}

// Kernel 1: dw[b,t,j] = (gelu(rms(x_cur) @ w1) @ w2)[j] + static_weight[j]
// (static_weight is [C,L] flat = index j = c*L + l, exactly the matmul's j)
__global__ __launch_bounds__(256, 2)
void dw_kernel(const float* __restrict__ xs,
               const float* __restrict__ w1,
               const float* __restrict__ w2,
               const float* __restrict__ sw,
               float* __restrict__ dw_out) {
    __shared__ float xls[TOK][ND];      // 64 KB: 8 token rows of x_current
    __shared__ float rinv_s[TOK];
    __shared__ float y_s[TOK][NH];
    const int tid  = threadIdx.x;
    const int wave = tid >> 6;
    const int lane = tid & 63;

    // stage 8 rows of x_current (l = NL-1)
    const float* xcur = xs + (long)(NL - 1) * BTD + (long)blockIdx.x * TOK * ND;
    const float4* src = (const float4*)xcur;
    float4* dst = (float4*)&xls[0][0];
    #pragma unroll
    for (int i = 0; i < (TOK * ND / 4) / 256; ++i)
        dst[tid + i * 256] = src[tid + i * 256];
    __syncthreads();

    // per-token sumsq -> rinv  (wave w handles tokens 2w, 2w+1)
    #pragma unroll
    for (int tt = 0; tt < 2; ++tt) {
        const int tok = wave * 2 + tt;
        float ss = 0.f;
        for (int d = lane; d < ND; d += 64) { float v = xls[tok][d]; ss += v * v; }
        #pragma unroll
        for (int off = 32; off; off >>= 1) ss += __shfl_xor(ss, off);
        if (lane == 0) rinv_s[tok] = rsqrtf(ss * (1.0f / ND) + 1e-6f);
    }
    __syncthreads();

    float rv[TOK];
    #pragma unroll
    for (int t = 0; t < TOK; ++t) rv[t] = rinv_s[t];

    // matvec: wave w computes y[h] for h in [12w, 12w+12), all 8 tokens
    float acc[TOK][12];
    #pragma unroll
    for (int t = 0; t < TOK; ++t)
        #pragma unroll
        for (int j = 0; j < 12; ++j) acc[t][j] = 0.f;

    const int h0 = wave * 12;
    for (int d = lane; d < ND; d += 64) {
        const float* wrow = w1 + (long)d * NH + h0;
        const float4 wA = *(const float4*)(wrow);
        const float4 wB = *(const float4*)(wrow + 4);
        const float4 wC = *(const float4*)(wrow + 8);
        #pragma unroll
        for (int t = 0; t < TOK; ++t) {
            const float xv = xls[t][d] * rv[t];
            acc[t][0]  += xv * wA.x; acc[t][1]  += xv * wA.y;
            acc[t][2]  += xv * wA.z; acc[t][3]  += xv * wA.w;
            acc[t][4]  += xv * wB.x; acc[t][5]  += xv * wB.y;
            acc[t][6]  += xv * wB.z; acc[t][7]  += xv * wB.w;
            acc[t][8]  += xv * wC.x; acc[t][9]  += xv * wC.y;
            acc[t][10] += xv * wC.z; acc[t][11] += xv * wC.w;
        }
    }
    // reduce each acc over the wave
    #pragma unroll
    for (int t = 0; t < TOK; ++t)
        #pragma unroll
        for (int j = 0; j < 12; ++j) {
            float v = acc[t][j];
            #pragma unroll
            for (int off = 32; off; off >>= 1) v += __shfl_xor(v, off);
            acc[t][j] = v;
        }
    if (lane == 0) {
        #pragma unroll
        for (int t = 0; t < TOK; ++t)
            #pragma unroll
            for (int j = 0; j < 12; ++j)
                y_s[t][h0 + j] = acc[t][j];
    }
    __syncthreads();

    // gelu in place
    for (int i = tid; i < TOK * NH; i += 256) {
        float* p = &y_s[0][0];
        p[i] = gelu_exact(p[i]);
    }
    __syncthreads();

    // z = g @ w2 + static_weight ; store
    for (int i = tid; i < TOK * NH; i += 256) {
        const int tok = i / NH;
        const int j   = i - tok * NH;
        float z = sw[j];
        #pragma unroll
        for (int h = 0; h < NH; ++h) z += y_s[tok][h] * w2[h * NH + j];
        dw_out[((long)blockIdx.x * TOK + tok) * NH + j] = z;
    }
}

// Kernel 2: per token, aggregate and write [C,B,T,D] output.
__global__ __launch_bounds__(256, 2)
void agg_kernel(const float* __restrict__ xs,
                const float* __restrict__ dw,
                const float* __restrict__ pre_scales,
                const float* __restrict__ post_scales,
                float* __restrict__ out) {
    const int tid  = threadIdx.x;
    const int wave = tid >> 6;
    const int lane = tid & 63;
    const long token = blockIdx.x;

    __shared__ float dw_s[NC * NL];
    __shared__ float rinv_s[NL];
    __shared__ float rinv2_s[NC];
    __shared__ float red[4][NL];
    __shared__ float red2[4][NC];

    if (tid < NC * NL) dw_s[tid] = dw[token * NC * NL + tid];

    // load all 12 layer rows for this token: 2 float4 per layer per thread
    float4 x[NL][2];
    #pragma unroll
    for (int l = 0; l < NL; ++l) {
        const float4* p = (const float4*)(xs + (long)l * BTD + token * ND);
        x[l][0] = p[tid];
        x[l][1] = p[tid + 256];
    }

    // per-layer sumsq
    float ss[NL];
    #pragma unroll
    for (int l = 0; l < NL; ++l) {
        const float4 a = x[l][0], b = x[l][1];
        ss[l] = a.x*a.x + a.y*a.y + a.z*a.z + a.w*a.w
              + b.x*b.x + b.y*b.y + b.z*b.z + b.w*b.w;
    }
    #pragma unroll
    for (int l = 0; l < NL; ++l) {
        float v = ss[l];
        #pragma unroll
        for (int off = 32; off; off >>= 1) v += __shfl_xor(v, off);
        if (lane == 0) red[wave][l] = v;
    }
    __syncthreads();
    if (tid < NL) {
        const float s = red[0][tid] + red[1][tid] + red[2][tid] + red[3][tid];
        rinv_s[tid] = rsqrtf(s * (1.0f / ND) + 1e-6f);
    }
    __syncthreads();

    float rvv[NL];
    #pragma unroll
    for (int l = 0; l < NL; ++l) rvv[l] = rinv_s[l];

    // aggregate 4 ways
    float4 acc[NC][2];
    #pragma unroll
    for (int c = 0; c < NC; ++c) {
        acc[c][0] = make_float4(0.f, 0.f, 0.f, 0.f);
        acc[c][1] = make_float4(0.f, 0.f, 0.f, 0.f);
    }
    #pragma unroll
    for (int l = 0; l < NL; ++l) {
        const float rv = rvv[l];
        const float4* ps = (const float4*)(pre_scales + (long)l * ND);
        const float4 p0 = ps[tid];
        const float4 p1 = ps[tid + 256];
        float4 xn0, xn1;
        xn0.x = x[l][0].x * rv * p0.x;  xn0.y = x[l][0].y * rv * p0.y;
        xn0.z = x[l][0].z * rv * p0.z;  xn0.w = x[l][0].w * rv * p0.w;
        xn1.x = x[l][1].x * rv * p1.x;  xn1.y = x[l][1].y * rv * p1.y;
        xn1.z = x[l][1].z * rv * p1.z;  xn1.w = x[l][1].w * rv * p1.w;
        #pragma unroll
        for (int c = 0; c < NC; ++c) {
            const float w = dw_s[c * NL + l];
            acc[c][0].x += w * xn0.x;  acc[c][0].y += w * xn0.y;
            acc[c][0].z += w * xn0.z;  acc[c][0].w += w * xn0.w;
            acc[c][1].x += w * xn1.x;  acc[c][1].y += w * xn1.y;
            acc[c][1].z += w * xn1.z;  acc[c][1].w += w * xn1.w;
        }
    }

    // sumsq of agg per way
    float ss2[NC];
    #pragma unroll
    for (int c = 0; c < NC; ++c) {
        const float4 a = acc[c][0], b = acc[c][1];
        ss2[c] = a.x*a.x + a.y*a.y + a.z*a.z + a.w*a.w
               + b.x*b.x + b.y*b.y + b.z*b.z + b.w*b.w;
    }
    #pragma unroll
    for (int c = 0; c < NC; ++c) {
        float v = ss2[c];
        #pragma unroll
        for (int off = 32; off; off >>= 1) v += __shfl_xor(v, off);
        if (lane == 0) red2[wave][c] = v;
    }
    __syncthreads();
    if (tid < NC) {
        const float s = red2[0][tid] + red2[1][tid] + red2[2][tid] + red2[3][tid];
        rinv2_s[tid] = rsqrtf(s * (1.0f / ND) + 1e-6f);
    }
    __syncthreads();

    // out = rms(agg) * post_scales + x_current
    #pragma unroll
    for (int c = 0; c < NC; ++c) {
        const float r2 = rinv2_s[c];
        const float4* po = (const float4*)(post_scales + (long)c * ND);
        const float4 q0 = po[tid];
        const float4 q1 = po[tid + 256];
        float4 o0, o1;
        o0.x = acc[c][0].x * r2 * q0.x + x[NL-1][0].x;
        o0.y = acc[c][0].y * r2 * q0.y + x[NL-1][0].y;
        o0.z = acc[c][0].z * r2 * q0.z + x[NL-1][0].z;
        o0.w = acc[c][0].w * r2 * q0.w + x[NL-1][0].w;
        o1.x = acc[c][1].x * r2 * q1.x + x[NL-1][1].x;
        o1.y = acc[c][1].y * r2 * q1.y + x[NL-1][1].y;
        o1.z = acc[c][1].z * r2 * q1.z + x[NL-1][1].z;
        o1.w = acc[c][1].w * r2 * q1.w + x[NL-1][1].w;
        float4* op = (float4*)(out + (long)c * BTD + token * ND);
        op[tid]       = o0;
        op[tid + 256] = o1;
    }
}

extern "C" void kernel_launch(void* const* d_in, const int* in_sizes, int n_in,
                              void* d_out, int out_size, void* d_ws, size_t ws_size,
                              hipStream_t stream) {
    const float* xs   = (const float*)d_in[0];
    const float* w1   = (const float*)d_in[1];
    const float* w2   = (const float*)d_in[2];
    const float* sw   = (const float*)d_in[3];
    const float* pre  = (const float*)d_in[4];
    const float* post = (const float*)d_in[5];
    float* out   = (float*)d_out;
    float* dw_ws = (float*)d_ws;   // 4096*48 floats = 786 KB

    dw_kernel<<<NBT / TOK, 256, 0, stream>>>(xs, w1, w2, sw, dw_ws);
    agg_kernel<<<NBT, 256, 0, stream>>>(xs, dw_ws, pre, post, out);
}